// Round 11
// baseline (153.029 us; speedup 1.0000x reference)
//
#include <hip/hip_runtime.h>

typedef __bf16 bf16x8 __attribute__((ext_vector_type(8)));
typedef float f32x4 __attribute__((ext_vector_type(4)));

__device__ __forceinline__ unsigned short f2b(float f) {
  union { float f; unsigned int u; } v;
  v.f = f;
  unsigned int r = v.u + 0x7fffu + ((v.u >> 16) & 1u);
  return (unsigned short)(r >> 16);
}
__device__ __forceinline__ float b2f_lo(unsigned int u) {
  union { unsigned int u; float f; } v;
  v.u = u << 16;
  return v.f;
}
__device__ __forceinline__ float b2f_hi(unsigned int u) {
  union { unsigned int u; float f; } v;
  v.u = u & 0xffff0000u;
  return v.f;
}

// ---------------- kernel 0: weight f32 [O][C][9] -> bf16 k-major [O][k*256+c] --
__global__ __launch_bounds__(256) void cast_weight(
    const float* __restrict__ w, unsigned short* __restrict__ wb) {
  int idx = blockIdx.x * 256 + threadIdx.x;  // 589824
  int o = idx / 2304;
  int r = idx - o * 2304;
  int k = r >> 8;
  int c = r & 255;
  wb[idx] = f2b(w[(size_t)(o * 256 + c) * 9 + k]);
}

// ---------------- kernel 1: x NCHW f32 -> NHWC bf16  x_t[b][h][w][c] ----------
__global__ __launch_bounds__(256) void transpose_x(
    const float* __restrict__ x, unsigned short* __restrict__ xt) {
  const int bid = blockIdx.x;
  const int b = bid >> 8;
  const int h = (bid >> 2) & 63;
  const int cq = bid & 3;
  const int t = threadIdx.x;
  const int wave = t >> 6, lane = t & 63;
  __shared__ float lds[64][65];
  const int wpos = t >> 2, sub = t & 3;
  const int cl0 = wave * 4 + (lane >> 4);
  const int w0 = (lane & 15) * 4;
#pragma unroll
  for (int iter = 0; iter < 4; ++iter) {
    const int cl = iter * 16 + cl0;
    const int c = cq * 64 + cl;
    float4 v = *(const float4*)(x + (((size_t)b * 256 + c) * 64 + h) * 64 + w0);
    lds[cl][w0] = v.x; lds[cl][w0 + 1] = v.y;
    lds[cl][w0 + 2] = v.z; lds[cl][w0 + 3] = v.w;
  }
  __syncthreads();
  unsigned short hb[16];
#pragma unroll
  for (int j = 0; j < 16; ++j) hb[j] = f2b(lds[sub * 16 + j][wpos]);
  uint4 p0, p1;
  p0.x = (unsigned)hb[0] | ((unsigned)hb[1] << 16);
  p0.y = (unsigned)hb[2] | ((unsigned)hb[3] << 16);
  p0.z = (unsigned)hb[4] | ((unsigned)hb[5] << 16);
  p0.w = (unsigned)hb[6] | ((unsigned)hb[7] << 16);
  p1.x = (unsigned)hb[8] | ((unsigned)hb[9] << 16);
  p1.y = (unsigned)hb[10] | ((unsigned)hb[11] << 16);
  p1.z = (unsigned)hb[12] | ((unsigned)hb[13] << 16);
  p1.w = (unsigned)hb[14] | ((unsigned)hb[15] << 16);
  unsigned short* dst = xt + (((size_t)b * 64 + h) * 64 + wpos) * 256 + cq * 64 + sub * 16;
  *(uint4*)dst = p0;
  *(uint4*)(dst + 8) = p1;
}

// ---------------- fused: A-in-registers, LDS only for B, lgkm-only barriers ---
// block = (b, nt=h, nq=16-pos quarter). Out tile [256 o][16 hw]. 72 tiles K=32,
// 36 barriers (2 tiles each). 256 thr = 4 waves m-split (64 rows, fm=4, fn=1).
// No global_load_lds anywhere: A goes global->VGPR per wave (rows wave-private),
// taps global->VGPR with 1-superphase slack; barriers wait ONLY lgkmcnt(0).
__global__ __launch_bounds__(256, 4) void dcn_fused(
    const unsigned short* __restrict__ xt, const float* __restrict__ off,
    const float* __restrict__ mask, const __bf16* __restrict__ wbf,
    const float* __restrict__ bias, float* __restrict__ out) {
  __shared__ __align__(16) __bf16 Bs[4][16][32];          // 4 KB ring
  __shared__ __align__(16) float swt[9][16][4];           // 2304 B
  __shared__ __align__(8) unsigned short sidx[9][16][4];  // 1152 B

  const int bid = blockIdx.x;
  const int id = ((bid & 7) << 7) | (bid >> 3);  // bijective (1024 = 8*128)
  const int b = id >> 8;
  const int nt = (id >> 2) & 63;  // h row
  const int nq = id & 3;          // 16-pos quarter: w in [nq*16, nq*16+16)

  const int tid = threadIdx.x;
  const int lane = tid & 63;
  const int wave = tid >> 6;  // 4 waves, m-split 64 rows each
  const int lh = lane & 15, lg = lane >> 4;

  // ---- precompute per-(pos,k) tap weights & packed indices ----
  if (tid < 144) {
    const int k = tid >> 4;   // 0..8
    const int pl = tid & 15;  // 0..15
    const int w = nq * 16 + pl;
    float oy = off[(((size_t)b * 18 + 2 * k) * 64 + nt) * 64 + w];
    float ox = off[(((size_t)b * 18 + 2 * k + 1) * 64 + nt) * 64 + w];
    float m = mask[(((size_t)b * 9 + k) * 64 + nt) * 64 + w];
    float py = oy + (float)(nt - 1 + k / 3);
    float px = ox + (float)(w - 1 + k % 3);
    float y0f = floorf(py), x0f = floorf(px);
    float ly = py - y0f, lx = px - x0f;
    float hy = 1.f - ly, hx = 1.f - lx;
    int y0 = (int)y0f, x0 = (int)x0f;
    int y1 = y0 + 1, x1 = x0 + 1;
    bool vy0 = (y0 >= 0) && (y0 < 64);
    bool vy1 = (y1 >= 0) && (y1 < 64);
    bool vx0 = (x0 >= 0) && (x0 < 64);
    bool vx1 = (x1 >= 0) && (x1 < 64);
    int yc0 = min(max(y0, 0), 63), yc1 = min(max(y1, 0), 63);
    int xc0 = min(max(x0, 0), 63), xc1 = min(max(x1, 0), 63);
    sidx[k][pl][0] = (unsigned short)(yc0 * 64 + xc0);
    sidx[k][pl][1] = (unsigned short)(yc0 * 64 + xc1);
    sidx[k][pl][2] = (unsigned short)(yc1 * 64 + xc0);
    sidx[k][pl][3] = (unsigned short)(yc1 * 64 + xc1);
    swt[k][pl][0] = (vy0 && vx0) ? hy * hx * m : 0.f;
    swt[k][pl][1] = (vy0 && vx1) ? hy * lx * m : 0.f;
    swt[k][pl][2] = (vy1 && vx0) ? ly * hx * m : 0.f;
    swt[k][pl][3] = (vy1 && vx1) ? ly * lx * m : 0.f;
  }

  // ---- A direct-to-reg geometry: lane (lh,lg) of wave holds A[row][k8] ----
  // row = wave*64 + fm*16 + lh ; uint4 = 8 bf16 at col TBASE(T) + lg*8.
  const uint4* apf0 = (const uint4*)(wbf + (size_t)(wave * 64 + 0 * 16 + lh) * 2304) + lg;
  const uint4* apf1 = (const uint4*)(wbf + (size_t)(wave * 64 + 1 * 16 + lh) * 2304) + lg;
  const uint4* apf2 = (const uint4*)(wbf + (size_t)(wave * 64 + 2 * 16 + lh) * 2304) + lg;
  const uint4* apf3 = (const uint4*)(wbf + (size_t)(wave * 64 + 3 * 16 + lh) * 2304) + lg;
#define AIDX(T) (((T) >> 3) * 32 + ((T) & 7) * 4)  // uint4 index for tile T

  // ---- B build: every thread combines 2 channels of one position ----
  const int pos = tid >> 4;  // 0..15
  const int cp = tid & 15;   // channel pair
  const unsigned short* xtb = xt + (size_t)b * 1048576 + cp * 2;

#define LOADA(T, R0, R1, R2, R3)                                                   \
  do {                                                                             \
    R0 = apf0[AIDX(T)];                                                            \
    R1 = apf1[AIDX(T)];                                                            \
    R2 = apf2[AIDX(T)];                                                            \
    R3 = apf3[AIDX(T)];                                                            \
  } while (0)

#define LOADTAPS(T, Q0, Q1, Q2, Q3)                                                \
  do {                                                                             \
    uint2 su = *(const uint2*)&sidx[(T) >> 3][pos][0];                             \
    const int co = ((T) & 7) * 32;                                                 \
    Q0 = *(const unsigned int*)(xtb + ((su.x & 0xFFFFu) << 8) + co);               \
    Q1 = *(const unsigned int*)(xtb + ((su.x >> 16) << 8) + co);                   \
    Q2 = *(const unsigned int*)(xtb + ((su.y & 0xFFFFu) << 8) + co);               \
    Q3 = *(const unsigned int*)(xtb + ((su.y >> 16) << 8) + co);                   \
  } while (0)

#define COMBINE(T, Q0, Q1, Q2, Q3)                                                 \
  do {                                                                             \
    float4 wt4 = *(const float4*)&swt[(T) >> 3][pos][0];                           \
    float v0 = wt4.x * b2f_lo(Q0) + wt4.y * b2f_lo(Q1) +                           \
               wt4.z * b2f_lo(Q2) + wt4.w * b2f_lo(Q3);                            \
    float v1 = wt4.x * b2f_hi(Q0) + wt4.y * b2f_hi(Q1) +                           \
               wt4.z * b2f_hi(Q2) + wt4.w * b2f_hi(Q3);                            \
    ((unsigned int*)&Bs[(T) & 3][pos][0])[cp] =                                    \
        (unsigned)f2b(v0) | ((unsigned)f2b(v1) << 16);                             \
  } while (0)

#define MFMA_T(T, R0, R1, R2, R3)                                                  \
  do {                                                                             \
    bf16x8 bv = *(const bf16x8*)&Bs[(T) & 3][lh][lg * 8];                          \
    acc[0] = __builtin_amdgcn_mfma_f32_16x16x32_bf16(*(bf16x8*)&R0, bv, acc[0],    \
                                                     0, 0, 0);                     \
    acc[1] = __builtin_amdgcn_mfma_f32_16x16x32_bf16(*(bf16x8*)&R1, bv, acc[1],    \
                                                     0, 0, 0);                     \
    acc[2] = __builtin_amdgcn_mfma_f32_16x16x32_bf16(*(bf16x8*)&R2, bv, acc[2],    \
                                                     0, 0, 0);                     \
    acc[3] = __builtin_amdgcn_mfma_f32_16x16x32_bf16(*(bf16x8*)&R3, bv, acc[3],    \
                                                     0, 0, 0);                     \
  } while (0)

#define BAR()                                                                      \
  do {                                                                             \
    asm volatile("s_waitcnt lgkmcnt(0)" ::: "memory");                             \
    __builtin_amdgcn_sched_barrier(0);                                             \
    __builtin_amdgcn_s_barrier();                                                  \
    __builtin_amdgcn_sched_barrier(0);                                             \
  } while (0)

  f32x4 acc[4] = {};
  uint4 ae0, ae1, ae2, ae3, ao0, ao1, ao2, ao3;
  unsigned int te0, te1, te2, te3, te4, te5, te6, te7;
  unsigned int to0, to1, to2, to3, to4, to5, to6, to7;

  __syncthreads();  // swt/sidx ready

  // ---- prologue: combine tiles {0,1} -> slots {0,1}; A{0,1}; taps{2,3} ----
  LOADTAPS(0, te0, te1, te2, te3);
  LOADTAPS(1, te4, te5, te6, te7);
  COMBINE(0, te0, te1, te2, te3);
  COMBINE(1, te4, te5, te6, te7);
  LOADA(0, ae0, ae1, ae2, ae3);
  LOADA(1, ao0, ao1, ao2, ao3);
  LOADTAPS(2, to0, to1, to2, to3);
  LOADTAPS(3, to4, to5, to6, to7);
  BAR();

  for (int p = 0; p < 17; ++p) {
    const int t = p * 4;
    // S = 2p: MFMA {t,t+1}; load A{t+2,t+3}, taps{t+4,t+5}; combine {t+2,t+3}
    MFMA_T(t + 0, ae0, ae1, ae2, ae3);
    LOADA(t + 2, ae0, ae1, ae2, ae3);
    MFMA_T(t + 1, ao0, ao1, ao2, ao3);
    LOADA(t + 3, ao0, ao1, ao2, ao3);
    LOADTAPS(t + 4, te0, te1, te2, te3);
    LOADTAPS(t + 5, te4, te5, te6, te7);
    COMBINE(t + 2, to0, to1, to2, to3);
    COMBINE(t + 3, to4, to5, to6, to7);
    BAR();
    // S = 2p+1: MFMA {t+2,t+3}; load A{t+4,t+5}, taps{t+6,t+7}; combine {t+4,t+5}
    MFMA_T(t + 2, ae0, ae1, ae2, ae3);
    LOADA(t + 4, ae0, ae1, ae2, ae3);
    MFMA_T(t + 3, ao0, ao1, ao2, ao3);
    LOADA(t + 5, ao0, ao1, ao2, ao3);
    // NOTE: no guard here — at p==16 this loads taps{70,71}, needed by the tail
    // (R10 bug: skipping these made tiles 70/71 combine with stale taps).
    LOADTAPS(t + 6, to0, to1, to2, to3);
    LOADTAPS(t + 7, to4, to5, to6, to7);
    COMBINE(t + 4, te0, te1, te2, te3);
    COMBINE(t + 5, te4, te5, te6, te7);
    BAR();
  }
  // p=16 end state: MFMA'd 0..67; A{68,69} in ae/ao; taps{70,71} in to;
  // combined tiles 68,69 (slots 0,1).
  // ---- tail: S=34 ----
  MFMA_T(68, ae0, ae1, ae2, ae3);
  LOADA(70, ae0, ae1, ae2, ae3);
  MFMA_T(69, ao0, ao1, ao2, ao3);
  LOADA(71, ao0, ao1, ao2, ao3);
  COMBINE(70, to0, to1, to2, to3);
  COMBINE(71, to4, to5, to6, to7);
  BAR();
  MFMA_T(70, ae0, ae1, ae2, ae3);
  MFMA_T(71, ao0, ao1, ao2, ao3);

  // ---- epilogue ----
  float* outb = out + (size_t)b * 1048576 + (size_t)nt * 64 + nq * 16 + lh;
#pragma unroll
  for (int fm = 0; fm < 4; ++fm) {
#pragma unroll
    for (int i = 0; i < 4; ++i) {
      const int o = wave * 64 + fm * 16 + lg * 4 + i;
      outb[(size_t)o * 4096] = acc[fm][i] + bias[o];
    }
  }
#undef AIDX
#undef LOADA
#undef LOADTAPS
#undef COMBINE
#undef MFMA_T
#undef BAR
}

extern "C" void kernel_launch(void* const* d_in, const int* in_sizes, int n_in,
                              void* d_out, int out_size, void* d_ws, size_t ws_size,
                              hipStream_t stream) {
  const float* x = (const float*)d_in[0];
  const float* off = (const float*)d_in[1];
  const float* mask = (const float*)d_in[2];
  const float* wgt = (const float*)d_in[3];
  const float* bias = (const float*)d_in[4];
  float* out = (float*)d_out;

  unsigned short* wbf = (unsigned short*)d_ws;   // 256*2304 bf16 = 1.2 MB
  unsigned short* xtp = wbf + 589824ull;         // 4*64*64*256 bf16 = 8.4 MB

  cast_weight<<<2304, 256, 0, stream>>>(wgt, wbf);
  transpose_x<<<1024, 256, 0, stream>>>(x, xtp);
  dcn_fused<<<1024, 256, 0, stream>>>(xtp, off, mask, (const __bf16*)wbf, bias,
                                      out);
}

// Round 12
// 61.791 us; speedup vs baseline: 2.4766x; 2.4766x over previous
//
#include <hip/hip_runtime.h>

typedef _Float16 f16x8 __attribute__((ext_vector_type(8)));
typedef float f32x4 __attribute__((ext_vector_type(4)));

__device__ __forceinline__ unsigned short f2h(float f) {
  _Float16 h = (_Float16)f;
  union { _Float16 h; unsigned short u; } v;
  v.h = h;
  return v.u;
}
__device__ __forceinline__ f16x8 splat8(float w) {
  _Float16 h = (_Float16)w;
  f16x8 v = {h, h, h, h, h, h, h, h};
  return v;
}

// ---------------- kernel 0: merged prep ----------------
// bid < 1024: x NCHW f32 -> NHWC f16 xt[b][h][w][c]  (4 blocks/CU latency-hiding)
// bid >= 1024: weight f32 [O][C][9] -> f16 k-major [O][k*256+c] (576 blocks x 1024)
__global__ __launch_bounds__(256) void prep_wx(
    const float* __restrict__ x, const float* __restrict__ w,
    unsigned short* __restrict__ xt, unsigned short* __restrict__ wb) {
  const int bid = blockIdx.x;
  const int t = threadIdx.x;
  if (bid >= 1024) {
    const int idx4 = (bid - 1024) * 1024 + t * 4;  // 4 consecutive outputs
    const int o = idx4 / 2304;
    const int r = idx4 - o * 2304;
    const int k = r >> 8;
    const int c = r & 255;
    const float* src = w + (size_t)(o * 256 + c) * 9 + k;
    uint2 p;
    p.x = (unsigned)f2h(src[0]) | ((unsigned)f2h(src[9]) << 16);
    p.y = (unsigned)f2h(src[18]) | ((unsigned)f2h(src[27]) << 16);
    *(uint2*)(wb + idx4) = p;
    return;
  }
  const int b = bid >> 8;
  const int h = (bid >> 2) & 63;
  const int cq = bid & 3;
  const int wave = t >> 6, lane = t & 63;
  __shared__ float lds[64][65];
  const int wpos = t >> 2, sub = t & 3;
  const int cl0 = wave * 4 + (lane >> 4);
  const int w0 = (lane & 15) * 4;
#pragma unroll
  for (int iter = 0; iter < 4; ++iter) {
    const int cl = iter * 16 + cl0;
    const int c = cq * 64 + cl;
    float4 v = *(const float4*)(x + (((size_t)b * 256 + c) * 64 + h) * 64 + w0);
    lds[cl][w0] = v.x; lds[cl][w0 + 1] = v.y;
    lds[cl][w0 + 2] = v.z; lds[cl][w0 + 3] = v.w;
  }
  __syncthreads();
  unsigned short hb[16];
#pragma unroll
  for (int j = 0; j < 16; ++j) hb[j] = f2h(lds[sub * 16 + j][wpos]);
  uint4 p0, p1;
  p0.x = (unsigned)hb[0] | ((unsigned)hb[1] << 16);
  p0.y = (unsigned)hb[2] | ((unsigned)hb[3] << 16);
  p0.z = (unsigned)hb[4] | ((unsigned)hb[5] << 16);
  p0.w = (unsigned)hb[6] | ((unsigned)hb[7] << 16);
  p1.x = (unsigned)hb[8] | ((unsigned)hb[9] << 16);
  p1.y = (unsigned)hb[10] | ((unsigned)hb[11] << 16);
  p1.z = (unsigned)hb[12] | ((unsigned)hb[13] << 16);
  p1.w = (unsigned)hb[14] | ((unsigned)hb[15] << 16);
  unsigned short* dst = xt + (((size_t)b * 64 + h) * 64 + wpos) * 256 + cq * 64 + sub * 16;
  *(uint4*)dst = p0;
  *(uint4*)(dst + 8) = p1;
}

// ---------------- fused: sample + GEMM, BK=64 phases (R5 structure, f16) -----
// block = (b, nt=h). Out tile [256 o][64 hw]. 36 phases of K=64 (tap k = kt>>2,
// channel base (kt&3)*64). 512 threads = 8 waves (4m x 2n). Dynamic LDS 98KB.
// f16 data path: taps are packed f16 pairs; combine = v_pk_fma_f16, no unpack.
#define G2L(gsrc, ldst)                                                            \
  __builtin_amdgcn_global_load_lds(                                                \
      (const __attribute__((address_space(1))) void*)(gsrc),                       \
      (__attribute__((address_space(3))) void*)(ldst), 16, 0, 0)

__device__ __forceinline__ void combine8(uint4 q0, uint4 q1, uint4 q2, uint4 q3,
                                         float4 wt, _Float16* dst) {
  f16x8 t0, t1, t2, t3;
  __builtin_memcpy(&t0, &q0, 16);
  __builtin_memcpy(&t1, &q1, 16);
  __builtin_memcpy(&t2, &q2, 16);
  __builtin_memcpy(&t3, &q3, 16);
  f16x8 r = t0 * splat8(wt.x);
  r += t1 * splat8(wt.y);
  r += t2 * splat8(wt.z);
  r += t3 * splat8(wt.w);
  __builtin_memcpy(dst, &r, 16);
}

__global__ __launch_bounds__(512) void dcn_fused(
    const unsigned short* __restrict__ xt, const float* __restrict__ off,
    const float* __restrict__ mask, const _Float16* __restrict__ wbf,
    const float* __restrict__ bias, float* __restrict__ out) {
  extern __shared__ char smem_raw[];
  _Float16* As = (_Float16*)smem_raw;       // 2 bufs x 16384 el = 65536 B
  _Float16* Bs = As + 32768;                // 2 bufs x 4096 el  = 16384 B
  float* swt = (float*)(Bs + 8192);         // [9][64][4] = 9216 B
  int* sidx = (int*)(swt + 2304);           // [9][64][4] = 9216 B

  const int bid = blockIdx.x;
  const int id = ((bid & 7) << 5) | (bid >> 3);  // XCD-contiguous, bijective
  const int b = id >> 6;
  const int nt = id & 63;  // = h row

  const int tid = threadIdx.x;
  const int lane = tid & 63;
  const int wave = tid >> 6;
  const int wm = wave >> 1, wn = wave & 1;
  const int lh = lane & 15, lg = lane >> 4;

  // ---- precompute per-(pos,k) tap weights & indices ----
  for (int pair = tid; pair < 576; pair += 512) {
    const int k = pair >> 6;   // 0..8
    const int pl = pair & 63;  // = w
    float oy = off[(((size_t)b * 18 + 2 * k) * 64 + nt) * 64 + pl];
    float ox = off[(((size_t)b * 18 + 2 * k + 1) * 64 + nt) * 64 + pl];
    float m = mask[(((size_t)b * 9 + k) * 64 + nt) * 64 + pl];
    float py = oy + (float)(nt - 1 + k / 3);
    float px = ox + (float)(pl - 1 + k % 3);
    float y0f = floorf(py), x0f = floorf(px);
    float ly = py - y0f, lx = px - x0f;
    float hy = 1.f - ly, hx = 1.f - lx;
    int y0 = (int)y0f, x0 = (int)x0f;
    int y1 = y0 + 1, x1 = x0 + 1;
    bool vy0 = (y0 >= 0) && (y0 < 64);
    bool vy1 = (y1 >= 0) && (y1 < 64);
    bool vx0 = (x0 >= 0) && (x0 < 64);
    bool vx1 = (x1 >= 0) && (x1 < 64);
    int yc0 = min(max(y0, 0), 63), yc1 = min(max(y1, 0), 63);
    int xc0 = min(max(x0, 0), 63), xc1 = min(max(x1, 0), 63);
    int* sp = sidx + (k * 64 + pl) * 4;
    float* wp = swt + (k * 64 + pl) * 4;
    sp[0] = (yc0 * 64 + xc0) * 256;
    sp[1] = (yc0 * 64 + xc1) * 256;
    sp[2] = (yc1 * 64 + xc0) * 256;
    sp[3] = (yc1 * 64 + xc1) * 256;
    wp[0] = (vy0 && vx0) ? hy * hx * m : 0.f;
    wp[1] = (vy0 && vx1) ? hy * lx * m : 0.f;
    wp[2] = (vy1 && vx0) ? ly * hx * m : 0.f;
    wp[3] = (vy1 && vx1) ? ly * lx * m : 0.f;
  }

  // ---- A staging geometry (4 G2L per phase, 32-wide subtile swizzle) ----
  const _Float16* aSrc[4];
  int aDst[4];
#pragma unroll
  for (int j = 0; j < 4; ++j) {
    const int L = j * 512 + tid;
    const int ksj = L >> 10;
    const int r = L & 1023;
    const int row = r >> 2;
    const int swz = (r & 3) ^ ((row >> 1) & 3);
    aSrc[j] = wbf + (size_t)row * 2304 + ksj * 32 + swz * 8;
    aDst[j] = L * 8;  // element offset within an As buffer
  }

  // ---- B build geometry ----
  const int pos = tid >> 3, ci = tid & 7;
  const unsigned short* xtb = xt + (size_t)b * 1048576 + ci * 8;
  const int bsw = (ci >> 2) * 2048 + pos * 32 + (((ci & 3) ^ ((pos >> 1) & 3)) * 8);

  // ---- MFMA fragment offsets ----
  const int csw = (lg ^ ((lh >> 1) & 3)) * 8;
  int aoff[4], boff[2];
#pragma unroll
  for (int fm = 0; fm < 4; ++fm) aoff[fm] = (wm * 64 + fm * 16 + lh) * 32 + csw;
#pragma unroll
  for (int fn = 0; fn < 2; ++fn) boff[fn] = (wn * 32 + fn * 16 + lh) * 32 + csw;

#define MFMA_PHASE(BUF)                                                            \
  do {                                                                             \
    const _Float16* Ab = As + (BUF) * 16384;                                       \
    const _Float16* Bb = Bs + (BUF) * 4096;                                        \
    f16x8 a0[4], a1[4], b0[2], b1[2];                                              \
    _Pragma("unroll") for (int fm = 0; fm < 4; ++fm) {                             \
      a0[fm] = *(const f16x8*)(Ab + aoff[fm]);                                     \
      a1[fm] = *(const f16x8*)(Ab + 8192 + aoff[fm]);                              \
    }                                                                              \
    _Pragma("unroll") for (int fn = 0; fn < 2; ++fn) {                             \
      b0[fn] = *(const f16x8*)(Bb + boff[fn]);                                     \
      b1[fn] = *(const f16x8*)(Bb + 2048 + boff[fn]);                              \
    }                                                                              \
    _Pragma("unroll") for (int fm = 0; fm < 4; ++fm)                               \
        _Pragma("unroll") for (int fn = 0; fn < 2; ++fn) {                         \
      acc[fm][fn] = __builtin_amdgcn_mfma_f32_16x16x32_f16(a0[fm], b0[fn],         \
                                                           acc[fm][fn], 0, 0, 0); \
      acc[fm][fn] = __builtin_amdgcn_mfma_f32_16x16x32_f16(a1[fm], b1[fn],         \
                                                           acc[fm][fn], 0, 0, 0); \
    }                                                                              \
  } while (0)

#define WAIT_BAR(N)                                                                \
  do {                                                                             \
    asm volatile("s_waitcnt vmcnt(" #N ") lgkmcnt(0)" ::: "memory");               \
    __builtin_amdgcn_sched_barrier(0);                                             \
    __builtin_amdgcn_s_barrier();                                                  \
  } while (0)

#define STAGE_A(KT, BUF)                                                           \
  do {                                                                             \
    _Float16* AsD = As + (BUF) * 16384;                                            \
    G2L(aSrc[0] + (KT) * 64, AsD + aDst[0]);                                       \
    G2L(aSrc[1] + (KT) * 64, AsD + aDst[1]);                                       \
    G2L(aSrc[2] + (KT) * 64, AsD + aDst[2]);                                       \
    G2L(aSrc[3] + (KT) * 64, AsD + aDst[3]);                                       \
  } while (0)

#define LOADTAPS(Q0, Q1, Q2, Q3, IX, CO)                                           \
  do {                                                                             \
    Q0 = *(const uint4*)(xtb + (IX).x + (CO));                                     \
    Q1 = *(const uint4*)(xtb + (IX).y + (CO));                                     \
    Q2 = *(const uint4*)(xtb + (IX).z + (CO));                                     \
    Q3 = *(const uint4*)(xtb + (IX).w + (CO));                                     \
  } while (0)

  // phase p: G2L(tile p+1 -> As[(p+1)&1]); taps(tile p+2) -> qLoad;
  // combine(qComb = tile p+1, wt[(p+1)>>2]) -> Bs[(p+1)&1]; MFMA(tile p, buf p&1)
#define PHASE(P_, QL0, QL1, QL2, QL3, QC0, QC1, QC2, QC3)                          \
  do {                                                                             \
    const int kt1 = (P_) + 1, kt2 = (P_) + 2;                                      \
    const int BC = kt1 & 1;                                                        \
    STAGE_A(kt1, BC);                                                              \
    __builtin_amdgcn_sched_barrier(0);                                             \
    float4 wt4 = *(const float4*)(swt + ((kt1 >> 2) * 64 + pos) * 4);              \
    int4 ix = *(const int4*)(sidx + ((kt2 >> 2) * 64 + pos) * 4);                  \
    LOADTAPS(QL0, QL1, QL2, QL3, ix, (kt2 & 3) * 64);                              \
    combine8(QC0, QC1, QC2, QC3, wt4, Bs + BC * 4096 + bsw);                       \
    __builtin_amdgcn_s_setprio(1);                                                 \
    MFMA_PHASE((P_) & 1);                                                          \
    __builtin_amdgcn_s_setprio(0);                                                 \
    WAIT_BAR(4);                                                                   \
  } while (0)

  f32x4 acc[4][2] = {};
  uint4 qA0, qA1, qA2, qA3, qB0, qB1, qB2, qB3;

  __syncthreads();  // swt/sidx ready

  // ---- prologue: tile0 build + tile0 A-stage + tile1 taps ----
  {
    float4 wt0 = *(const float4*)(swt + pos * 4);
    int4 ix0 = *(const int4*)(sidx + pos * 4);
    LOADTAPS(qA0, qA1, qA2, qA3, ix0, 0);
    combine8(qA0, qA1, qA2, qA3, wt0, Bs + bsw);
    STAGE_A(0, 0);
    __builtin_amdgcn_sched_barrier(0);
    LOADTAPS(qB0, qB1, qB2, qB3, ix0, 64);
    WAIT_BAR(4);
  }

  for (int p = 0; p < 34; p += 2) {
    PHASE(p, qA0, qA1, qA2, qA3, qB0, qB1, qB2, qB3);
    PHASE(p + 1, qB0, qB1, qB2, qB3, qA0, qA1, qA2, qA3);
  }
  // ---- tail: phase 34 (no tap prefetch), phase 35 (MFMA only) ----
  {
    STAGE_A(35, 1);
    float4 wt4 = *(const float4*)(swt + (8 * 64 + pos) * 4);
    combine8(qB0, qB1, qB2, qB3, wt4, Bs + 4096 + bsw);
    __builtin_amdgcn_s_setprio(1);
    MFMA_PHASE(0);
    __builtin_amdgcn_s_setprio(0);
    WAIT_BAR(0);
    MFMA_PHASE(1);
  }

  // ---- epilogue ----
  float* outb = out + (size_t)b * 256 * 4096 + (size_t)nt * 64;
#pragma unroll
  for (int fm = 0; fm < 4; ++fm) {
#pragma unroll
    for (int i = 0; i < 4; ++i) {
      const int o = wm * 64 + fm * 16 + lg * 4 + i;
      const float bs = bias[o];
      float* orow = outb + (size_t)o * 4096 + wn * 32 + lh;
#pragma unroll
      for (int fn = 0; fn < 2; ++fn) orow[fn * 16] = acc[fm][fn][i] + bs;
    }
  }
#undef MFMA_PHASE
#undef WAIT_BAR
#undef STAGE_A
#undef LOADTAPS
#undef PHASE
}

extern "C" void kernel_launch(void* const* d_in, const int* in_sizes, int n_in,
                              void* d_out, int out_size, void* d_ws, size_t ws_size,
                              hipStream_t stream) {
  const float* x = (const float*)d_in[0];
  const float* off = (const float*)d_in[1];
  const float* mask = (const float*)d_in[2];
  const float* wgt = (const float*)d_in[3];
  const float* bias = (const float*)d_in[4];
  float* out = (float*)d_out;

  unsigned short* wbf = (unsigned short*)d_ws;   // 256*2304 f16 = 1.2 MB
  unsigned short* xtp = wbf + 589824ull;         // 4*64*64*256 f16 = 8.4 MB

  const int smem_bytes = 65536 + 16384 + 9216 + 9216;  // 100352
  (void)hipFuncSetAttribute(reinterpret_cast<const void*>(&dcn_fused),
                            hipFuncAttributeMaxDynamicSharedMemorySize, smem_bytes);

  prep_wx<<<1600, 256, 0, stream>>>(x, wgt, xtp, wbf);
  dcn_fused<<<256, 512, smem_bytes, stream>>>(xtp, off, mask,
                                              (const _Float16*)wbf, bias, out);
}

// Round 14
// 45.171 us; speedup vs baseline: 3.3878x; 1.3679x over previous
//
#include <hip/hip_runtime.h>

typedef _Float16 f16x8 __attribute__((ext_vector_type(8)));
typedef float f32x4 __attribute__((ext_vector_type(4)));

__device__ __forceinline__ unsigned short f2h(float f) {
  union { _Float16 h; unsigned short u; } v;
  v.h = (_Float16)f;
  return v.u;
}
__device__ __forceinline__ f16x8 splat8(float w) {
  _Float16 h = (_Float16)w;
  f16x8 v = {h, h, h, h, h, h, h, h};
  return v;
}

// ---------------- kernel 0: merged prep ----------------
// bid < 1024 : x NCHW f32 -> NHWC f16 xt[b][h][w][c]
// bid >= 1024: weight f32 [O][C][9] -> FRAG-MAJOR f16 wfrag[g][kt][lane][8]
//   g=row-group (o>>4), kt=K-tile of 32 (K=kk*256+c ordering), lane holds
//   A[o = g*16+(lane&15)][k = kt*32+(lane>>4)*8 + e], e=0..7. One uint4/slot.
__global__ __launch_bounds__(256) void prep_wx(
    const float* __restrict__ x, const float* __restrict__ w,
    unsigned short* __restrict__ xt, uint4* __restrict__ wfrag) {
  const int bid = blockIdx.x;
  const int t = threadIdx.x;
  if (bid >= 1024) {
    const int idx = (bid - 1024) * 256 + t;  // 0..73727
    const int l = idx & 63;
    const int kt = (idx >> 6) % 72;
    const int g = idx / (72 * 64);  // 0..15
    const int o = g * 16 + (l & 15);
    const int kbase = kt * 32 + ((l >> 4) * 8);
    unsigned short h[8];
#pragma unroll
    for (int e = 0; e < 8; ++e) {
      const int klin = kbase + e;
      const int kk = klin >> 8;
      const int c = klin & 255;
      h[e] = f2h(w[((size_t)o * 256 + c) * 9 + kk]);
    }
    uint4 p;
    p.x = (unsigned)h[0] | ((unsigned)h[1] << 16);
    p.y = (unsigned)h[2] | ((unsigned)h[3] << 16);
    p.z = (unsigned)h[4] | ((unsigned)h[5] << 16);
    p.w = (unsigned)h[6] | ((unsigned)h[7] << 16);
    wfrag[idx] = p;
    return;
  }
  const int b = bid >> 8;
  const int h = (bid >> 2) & 63;
  const int cq = bid & 3;
  const int wave = t >> 6, lane = t & 63;
  __shared__ float lds[64][65];
  const int wpos = t >> 2, sub = t & 3;
  const int cl0 = wave * 4 + (lane >> 4);
  const int w0 = (lane & 15) * 4;
#pragma unroll
  for (int iter = 0; iter < 4; ++iter) {
    const int cl = iter * 16 + cl0;
    const int c = cq * 64 + cl;
    float4 v = *(const float4*)(x + (((size_t)b * 256 + c) * 64 + h) * 64 + w0);
    lds[cl][w0] = v.x; lds[cl][w0 + 1] = v.y;
    lds[cl][w0 + 2] = v.z; lds[cl][w0 + 3] = v.w;
  }
  __syncthreads();
  unsigned short hb[16];
#pragma unroll
  for (int j = 0; j < 16; ++j) hb[j] = f2h(lds[sub * 16 + j][wpos]);
  uint4 p0, p1;
  p0.x = (unsigned)hb[0] | ((unsigned)hb[1] << 16);
  p0.y = (unsigned)hb[2] | ((unsigned)hb[3] << 16);
  p0.z = (unsigned)hb[4] | ((unsigned)hb[5] << 16);
  p0.w = (unsigned)hb[6] | ((unsigned)hb[7] << 16);
  p1.x = (unsigned)hb[8] | ((unsigned)hb[9] << 16);
  p1.y = (unsigned)hb[10] | ((unsigned)hb[11] << 16);
  p1.z = (unsigned)hb[12] | ((unsigned)hb[13] << 16);
  p1.w = (unsigned)hb[14] | ((unsigned)hb[15] << 16);
  unsigned short* dst = xt + (((size_t)b * 64 + h) * 64 + wpos) * 256 + cq * 64 + sub * 16;
  *(uint4*)dst = p0;
  *(uint4*)(dst + 8) = p1;
}

// ---------------- fused: A direct-to-VGPR (frag-major), lgkm-only barriers ----
// block = (b, nt=h). Out tile [256 o][64 hw]. 36 phases of K=64.
// 512 thr = 8 waves; each wave owns 32 rows (wv*32..wv*32+31): fm=2 x fn=4
// x 2 k-subtiles = 16 MFMA/phase/wave. LDS holds ONLY B ring (2x8KB) + tables.
// NO global_load_lds, NO vmcnt at barriers — A and taps certified by per-wave
// compiler-counted vmcnt.
__device__ __forceinline__ void combine8(uint4 q0, uint4 q1, uint4 q2, uint4 q3,
                                         float4 wt, _Float16* dst) {
  f16x8 t0, t1, t2, t3;
  __builtin_memcpy(&t0, &q0, 16);
  __builtin_memcpy(&t1, &q1, 16);
  __builtin_memcpy(&t2, &q2, 16);
  __builtin_memcpy(&t3, &q3, 16);
  f16x8 r = t0 * splat8(wt.x);
  r += t1 * splat8(wt.y);
  r += t2 * splat8(wt.z);
  r += t3 * splat8(wt.w);
  __builtin_memcpy(dst, &r, 16);
}

__global__ __launch_bounds__(512, 2) void dcn_fused(
    const unsigned short* __restrict__ xt, const float* __restrict__ off,
    const float* __restrict__ mask, const uint4* __restrict__ wfrag,
    const float* __restrict__ bias, float* __restrict__ out) {
  __shared__ __align__(16) _Float16 Bs[2][4096];  // 16 KB ring
  __shared__ __align__(16) float swt[9 * 64 * 4];   // 9216 B
  __shared__ __align__(16) int sidx[9 * 64 * 4];    // 9216 B

  const int bid = blockIdx.x;
  const int id = ((bid & 7) << 5) | (bid >> 3);  // XCD-contiguous, bijective
  const int b = id >> 6;
  const int nt = id & 63;  // h row

  const int tid = threadIdx.x;
  const int lane = tid & 63;
  const int wv = tid >> 6;  // 8 waves; wave owns rows wv*32..wv*32+31
  const int lh = lane & 15, lg = lane >> 4;

  // ---- precompute per-(pos,k) tap weights & indices ----
  for (int pair = tid; pair < 576; pair += 512) {
    const int k = pair >> 6;   // 0..8
    const int pl = pair & 63;  // = w
    float oy = off[(((size_t)b * 18 + 2 * k) * 64 + nt) * 64 + pl];
    float ox = off[(((size_t)b * 18 + 2 * k + 1) * 64 + nt) * 64 + pl];
    float m = mask[(((size_t)b * 9 + k) * 64 + nt) * 64 + pl];
    float py = oy + (float)(nt - 1 + k / 3);
    float px = ox + (float)(pl - 1 + k % 3);
    float y0f = floorf(py), x0f = floorf(px);
    float ly = py - y0f, lx = px - x0f;
    float hy = 1.f - ly, hx = 1.f - lx;
    int y0 = (int)y0f, x0 = (int)x0f;
    int y1 = y0 + 1, x1 = x0 + 1;
    bool vy0 = (y0 >= 0) && (y0 < 64);
    bool vy1 = (y1 >= 0) && (y1 < 64);
    bool vx0 = (x0 >= 0) && (x0 < 64);
    bool vx1 = (x1 >= 0) && (x1 < 64);
    int yc0 = min(max(y0, 0), 63), yc1 = min(max(y1, 0), 63);
    int xc0 = min(max(x0, 0), 63), xc1 = min(max(x1, 0), 63);
    int* sp = sidx + (k * 64 + pl) * 4;
    float* wp = swt + (k * 64 + pl) * 4;
    sp[0] = (yc0 * 64 + xc0) * 256;
    sp[1] = (yc0 * 64 + xc1) * 256;
    sp[2] = (yc1 * 64 + xc0) * 256;
    sp[3] = (yc1 * 64 + xc1) * 256;
    wp[0] = (vy0 && vx0) ? hy * hx * m : 0.f;
    wp[1] = (vy0 && vx1) ? hy * lx * m : 0.f;
    wp[2] = (vy1 && vx0) ? ly * hx * m : 0.f;
    wp[3] = (vy1 && vx1) ? ly * lx * m : 0.f;
  }

  // ---- A geometry: coalesced frag-major loads; wave owns groups wv*2, wv*2+1 ----
  const uint4* aBase = wfrag + (size_t)(wv * 2) * 72 * 64 + lane;

  // ---- B build geometry (identical to R12, verified) ----
  const int pos = tid >> 3, ci = tid & 7;
  const unsigned short* xtb = xt + (size_t)b * 1048576 + ci * 8;
  const int bsw = (ci >> 2) * 2048 + pos * 32 + (((ci & 3) ^ ((pos >> 1) & 3)) * 8);

  // ---- MFMA B-fragment offsets ----
  const int csw = (lg ^ ((lh >> 1) & 3)) * 8;
  int boff[4];
#pragma unroll
  for (int fn = 0; fn < 4; ++fn) boff[fn] = (fn * 16 + lh) * 32 + csw;

  // AR[j]: j&1 = row-group (fm), j>>1 = k-subtile. Max elem index:
  // (15*72 + 71)*64 + 63 = 73727 < 73728 (in-bounds).
#define LOADA(P, AR)                                                               \
  do {                                                                             \
    _Pragma("unroll") for (int j = 0; j < 4; ++j)                                  \
        AR[j] = aBase[(size_t)((((j & 1) * 72) + 2 * (P) + (j >> 1)) * 64)];       \
  } while (0)

#define LOADTAPS(Q0, Q1, Q2, Q3, IX, CO)                                           \
  do {                                                                             \
    Q0 = *(const uint4*)(xtb + (IX).x + (CO));                                     \
    Q1 = *(const uint4*)(xtb + (IX).y + (CO));                                     \
    Q2 = *(const uint4*)(xtb + (IX).z + (CO));                                     \
    Q3 = *(const uint4*)(xtb + (IX).w + (CO));                                     \
  } while (0)

#define MFMA_PHASE(BUF, AR)                                                        \
  do {                                                                             \
    const _Float16* Bb = &Bs[BUF][0];                                              \
    f16x8 b0[4], b1[4];                                                            \
    _Pragma("unroll") for (int fn = 0; fn < 4; ++fn) {                             \
      b0[fn] = *(const f16x8*)(Bb + boff[fn]);                                     \
      b1[fn] = *(const f16x8*)(Bb + 2048 + boff[fn]);                              \
    }                                                                              \
    __builtin_amdgcn_s_setprio(1);                                                 \
    _Pragma("unroll") for (int fm = 0; fm < 2; ++fm)                               \
        _Pragma("unroll") for (int fn = 0; fn < 4; ++fn) {                         \
      acc[fm][fn] = __builtin_amdgcn_mfma_f32_16x16x32_f16(                        \
          *(const f16x8*)&AR[fm], b0[fn], acc[fm][fn], 0, 0, 0);                   \
      acc[fm][fn] = __builtin_amdgcn_mfma_f32_16x16x32_f16(                        \
          *(const f16x8*)&AR[2 + fm], b1[fn], acc[fm][fn], 0, 0, 0);               \
    }                                                                              \
    __builtin_amdgcn_s_setprio(0);                                                 \
  } while (0)

#define BAR()                                                                      \
  do {                                                                             \
    asm volatile("s_waitcnt lgkmcnt(0)" ::: "memory");                             \
    __builtin_amdgcn_sched_barrier(0);                                             \
    __builtin_amdgcn_s_barrier();                                                  \
    __builtin_amdgcn_sched_barrier(0);                                             \
  } while (0)

  // phase p: A(p+1)->AL; taps(p+2)->QL; MFMA(p) from AC+Bs[p&1];
  // combine(taps p+1 = QC)->Bs[(p+1)&1]; BAR (lgkm only).
#define PHASE(P_, AL, AC, QL0, QL1, QL2, QL3, QC0, QC1, QC2, QC3)                  \
  do {                                                                             \
    LOADA((P_) + 1, AL);                                                           \
    int4 ix = *(const int4*)(sidx + ((((P_) + 2) >> 2) * 64 + pos) * 4);           \
    LOADTAPS(QL0, QL1, QL2, QL3, ix, (((P_) + 2) & 3) * 64);                       \
    float4 wt4 = *(const float4*)(swt + ((((P_) + 1) >> 2) * 64 + pos) * 4);       \
    MFMA_PHASE((P_) & 1, AC);                                                      \
    combine8(QC0, QC1, QC2, QC3, wt4, &Bs[((P_) + 1) & 1][0] + bsw);               \
    BAR();                                                                         \
  } while (0)

  f32x4 acc[2][4] = {};
  uint4 AE[4], AO[4];
  uint4 qA0, qA1, qA2, qA3, qB0, qB1, qB2, qB3;

  __syncthreads();  // swt/sidx ready

  // ---- prologue: combine tile 0 -> Bs[0]; A(0)->AE; taps(1)->qB ----
  {
    float4 wt0 = *(const float4*)(swt + pos * 4);
    int4 ix0 = *(const int4*)(sidx + pos * 4);
    LOADTAPS(qA0, qA1, qA2, qA3, ix0, 0);
    combine8(qA0, qA1, qA2, qA3, wt0, &Bs[0][0] + bsw);
    LOADA(0, AE);
    LOADTAPS(qB0, qB1, qB2, qB3, ix0, 64);
    BAR();
  }

  for (int p = 0; p < 34; p += 2) {
    PHASE(p, AO, AE, qA0, qA1, qA2, qA3, qB0, qB1, qB2, qB3);
    PHASE(p + 1, AE, AO, qB0, qB1, qB2, qB3, qA0, qA1, qA2, qA3);
  }
  // ---- tail: phase 34 (no tap prefetch), phase 35 (MFMA only) ----
  {
    LOADA(35, AO);
    float4 wt4 = *(const float4*)(swt + (8 * 64 + pos) * 4);
    MFMA_PHASE(0, AE);                                   // tile 34
    combine8(qB0, qB1, qB2, qB3, wt4, &Bs[1][0] + bsw);  // tile 35
    BAR();
    MFMA_PHASE(1, AO);                                   // tile 35
  }

  // ---- epilogue ----
  float* outb = out + (size_t)b * 1048576 + (size_t)nt * 64;
#pragma unroll
  for (int fm = 0; fm < 2; ++fm) {
#pragma unroll
    for (int i = 0; i < 4; ++i) {
      const int o = wv * 32 + fm * 16 + lg * 4 + i;
      const float bs = bias[o];
      float* orow = outb + (size_t)o * 4096 + lh;
#pragma unroll
      for (int fn = 0; fn < 4; ++fn) orow[fn * 16] = acc[fm][fn][i] + bs;
    }
  }
#undef LOADA
#undef LOADTAPS
#undef MFMA_PHASE
#undef BAR
#undef PHASE
}

extern "C" void kernel_launch(void* const* d_in, const int* in_sizes, int n_in,
                              void* d_out, int out_size, void* d_ws, size_t ws_size,
                              hipStream_t stream) {
  const float* x = (const float*)d_in[0];
  const float* off = (const float*)d_in[1];
  const float* mask = (const float*)d_in[2];
  const float* wgt = (const float*)d_in[3];
  const float* bias = (const float*)d_in[4];
  float* out = (float*)d_out;

  uint4* wfrag = (uint4*)d_ws;                              // 73728*16B = 1.18 MB
  unsigned short* xtp = (unsigned short*)(wfrag + 73728);   // 8.4 MB

  prep_wx<<<1312, 256, 0, stream>>>(x, wgt, xtp, wfrag);
  dcn_fused<<<256, 512, 0, stream>>>(xtp, off, mask, wfrag, bias, out);
}